// Round 2
// baseline (33.875 us; speedup 1.0000x reference)
//
#include <hip/hip_runtime.h>

#define NVAR   120    // 15 persons + 105 pair z-nodes
#define NGRAPH 680    // 120 vars + 105 h-factors + 455 g-factors

// pair index for a<b among N=15
__device__ __forceinline__ int pair_index(int a, int b) {
    return a * (29 - a) / 2 + (b - a - 1);
}
__device__ __forceinline__ void pair_invert(int f, int& u, int& v) {
    int a = 0;
    while (f >= 14 - a) { f -= 14 - a; a++; }
    u = a; v = a + 1 + f;
}
__device__ __forceinline__ void triple_invert(int t, int& a, int& b, int& c) {
    int x = 0;
    while (t >= (14 - x) * (13 - x) / 2) { t -= (14 - x) * (13 - x) / 2; x++; }
    a = x;
    int y = x + 1;
    while (t >= 14 - y) { t -= 14 - y; y++; }
    b = y; c = y + 1 + t;
}

#define FMA4(acc, s, wv)              \
    acc[0] = fmaf(s, wv.x, acc[0]);   \
    acc[1] = fmaf(s, wv.y, acc[1]);   \
    acc[2] = fmaf(s, wv.z, acc[2]);   \
    acc[3] = fmaf(s, wv.w, acc[3]);

// One block = (batch b, column half). Computes P-slice (16 of 32 GEMM cols)
// into LDS, then the 680x8 output slice. Single launch, no global scratch.
__global__ __launch_bounds__(256) void fgnn_fused(
    const float* __restrict__ vf,    // [64][120][128]
    const float* __restrict__ W,     // [256][16]
    const float* __restrict__ bias,  // [16]
    float* __restrict__ out)         // [64][680][16]
{
    __shared__ float Ps[120][8];   // self (S) columns, bias folded
    __shared__ float Pt[120][8];   // neighbor (T) columns
    __shared__ float TH[105][8];   // h-factor T-means (3x reuse)

    const int tid  = threadIdx.x;
    const int b    = blockIdx.x >> 1;
    const int half = blockIdx.x & 1;
    const int ch   = half * 8;     // global output-column base (0 or 8)

    const float* vfb = vf + (size_t)b * NVAR * 128;

    // ---------------- phase 1: P = vf @ W (2 rows x 4 cols per thread) ----
    if (tid < 240) {
        const int cg  = tid & 3;          // 0,1 = S quads; 2,3 = T quads
        const int rg  = tid >> 2;         // 0..59 -> rows 2rg, 2rg+1
        const int isT = cg >> 1;
        const int c0  = ch + (cg & 1) * 4;   // column offset within W row
        const int r0  = rg * 2;
        const float* wb = W + isT * 2048 + c0;           // 128*16 per half
        const float4* va = (const float4*)(vfb + (size_t)r0 * 128);
        const float4* vb = (const float4*)(vfb + (size_t)(r0 + 1) * 128);

        float acc0[4] = {0.f, 0.f, 0.f, 0.f};
        float acc1[4] = {0.f, 0.f, 0.f, 0.f};
        #pragma unroll
        for (int k4 = 0; k4 < 32; k4++) {
            float4 a0 = va[k4];
            float4 a1 = vb[k4];
            float4 w0 = *(const float4*)(wb + (k4 * 4 + 0) * 16);
            float4 w1 = *(const float4*)(wb + (k4 * 4 + 1) * 16);
            float4 w2 = *(const float4*)(wb + (k4 * 4 + 2) * 16);
            float4 w3 = *(const float4*)(wb + (k4 * 4 + 3) * 16);
            FMA4(acc0, a0.x, w0) FMA4(acc0, a0.y, w1)
            FMA4(acc0, a0.z, w2) FMA4(acc0, a0.w, w3)
            FMA4(acc1, a1.x, w0) FMA4(acc1, a1.y, w1)
            FMA4(acc1, a1.z, w2) FMA4(acc1, a1.w, w3)
        }

        const int cl = (cg & 1) * 4;      // 0 or 4 within our 8-col slice
        if (!isT) {
            #pragma unroll
            for (int j = 0; j < 4; j++) {
                float bj = bias[c0 + j];
                Ps[r0][cl + j]     = acc0[j] + bj;
                Ps[r0 + 1][cl + j] = acc1[j] + bj;
            }
        } else {
            #pragma unroll
            for (int j = 0; j < 4; j++) {
                Pt[r0][cl + j]     = acc0[j];
                Pt[r0 + 1][cl + j] = acc1[j];
            }
        }
    }
    __syncthreads();

    // ---------------- phase 1.5: h-factor T-means --------------------------
    for (int idx = tid; idx < 105 * 8; idx += 256) {
        int f = idx >> 3, c = idx & 7;
        int u, v; pair_invert(f, u, v);
        TH[f][c] = (Pt[u][c] + Pt[v][c] + Pt[15 + f][c]) * (1.0f / 3.0f);
    }
    __syncthreads();

    // ---------------- phase 2: all 680 x 8 outputs -------------------------
    const float inv3  = 1.0f / 3.0f;
    const float inv14 = 1.0f / 14.0f;
    float* outb = out + (size_t)b * NGRAPH * 16 + ch;

    for (int idx = tid; idx < NGRAPH * 8; idx += 256) {
        int i = idx >> 3, c = idx & 7;
        float res;
        if (i < 15) {
            // person u: 14 h-factor neighbors
            float s = Ps[i][c];
            float acc = 0.0f;
            #pragma unroll
            for (int v2 = 0; v2 < 15; v2++) {
                if (v2 == i) continue;
                int a = min(i, v2), d = max(i, v2);
                acc += fmaxf(s + TH[pair_index(a, d)][c], 0.0f);
            }
            res = acc * inv14;
        } else if (i < 120) {
            // pair z-node: 1 h-factor + 13 g-factors
            int f = i - 15;
            int u, v; pair_invert(f, u, v);
            float s = Ps[i][c], Tz = Pt[i][c];
            float acc = fmaxf(s + TH[f][c], 0.0f);
            #pragma unroll
            for (int w = 0; w < 15; w++) {
                if (w == u || w == v) continue;
                int zuw = 15 + pair_index(min(u, w), max(u, w));
                int zvw = 15 + pair_index(min(v, w), max(v, w));
                float Tg = (Tz + Pt[zuw][c] + Pt[zvw][c]) * inv3;
                acc += fmaxf(s + Tg, 0.0f);
            }
            res = acc * inv14;
        } else if (i < 225) {
            // h-factor row: neighbors [u, v, z x12]
            int f = i - 120;
            int u, v; pair_invert(f, u, v);
            int z = 15 + f;
            float S = (Ps[u][c] + Ps[v][c] + Ps[z][c]) * inv3;
            res = (fmaxf(S + Pt[u][c], 0.0f) + fmaxf(S + Pt[v][c], 0.0f)
                 + 12.0f * fmaxf(S + Pt[z][c], 0.0f)) * inv14;
        } else {
            // g-factor row: neighbors [z1, z2, z3 x12]
            int t = i - 225;
            int a, b2, c3; triple_invert(t, a, b2, c3);
            int z1 = 15 + pair_index(a, b2);
            int z2 = 15 + pair_index(a, c3);
            int z3 = 15 + pair_index(b2, c3);
            float S = (Ps[z1][c] + Ps[z2][c] + Ps[z3][c]) * inv3;
            res = (fmaxf(S + Pt[z1][c], 0.0f) + fmaxf(S + Pt[z2][c], 0.0f)
                 + 12.0f * fmaxf(S + Pt[z3][c], 0.0f)) * inv14;
        }
        outb[(size_t)i * 16 + c] = res;
    }
}

extern "C" void kernel_launch(void* const* d_in, const int* in_sizes, int n_in,
                              void* d_out, int out_size, void* d_ws, size_t ws_size,
                              hipStream_t stream) {
    const float* vf   = (const float*)d_in[0];  // [64,120,128]
    const float* W    = (const float*)d_in[1];  // [256,16]
    const float* bias = (const float*)d_in[2];  // [16]
    float* o = (float*)d_out;                   // [64,680,16]

    fgnn_fused<<<128, 256, 0, stream>>>(vf, W, bias, o);
}

// Round 3
// 27.660 us; speedup vs baseline: 1.2247x; 1.2247x over previous
//
#include <hip/hip_runtime.h>

#define NVAR   120    // 15 persons + 105 pair z-nodes
#define NGRAPH 680    // 120 vars + 105 h-factors + 455 g-factors

// pair index for a<b among N=15
__device__ __forceinline__ int pair_index(int a, int b) {
    return a * (29 - a) / 2 + (b - a - 1);
}

// ---- compile-time structure tables (graph is fixed) -----------------------
struct PairTab { unsigned char u[105]; unsigned char v[105]; };
__device__ constexpr PairTab make_pair_tab() {
    PairTab t{};
    int f = 0;
    for (int a = 0; a < 15; a++)
        for (int b = a + 1; b < 15; b++) { t.u[f] = (unsigned char)a; t.v[f] = (unsigned char)b; f++; }
    return t;
}
__device__ constexpr PairTab PAIRS = make_pair_tab();

struct TriTab { unsigned char z1[455]; unsigned char z2[455]; unsigned char z3[455]; };
__device__ constexpr TriTab make_tri_tab() {
    TriTab t{};
    int n = 0;
    for (int i = 0; i < 15; i++)
        for (int j = i + 1; j < 15; j++)
            for (int k = j + 1; k < 15; k++) {
                t.z1[n] = (unsigned char)(15 + i * (29 - i) / 2 + (j - i - 1));
                t.z2[n] = (unsigned char)(15 + i * (29 - i) / 2 + (k - i - 1));
                t.z3[n] = (unsigned char)(15 + j * (29 - j) / 2 + (k - j - 1));
                n++;
            }
    return t;
}
__device__ constexpr TriTab TRI = make_tri_tab();

// One block = (col-slice s, batch b): computes P[:, {c0,c0+1}] (S & T halves)
// into LDS, then the 680 x 2 output slice. 512 blocks total.
// Grid is slice-major so the 8 blocks of one batch share an XCD (L2 merge of
// partial output lines + vf reuse).
__global__ __launch_bounds__(256) void fgnn_fused(
    const float* __restrict__ vf,    // [64][120][128]
    const float* __restrict__ W,     // [256][16]
    const float* __restrict__ bias,  // [16]
    float* __restrict__ out)         // [64][680][16]
{
    __shared__ float Ps[120][3];   // stride-3 pad (odd) to spread banks
    __shared__ float Pt[120][3];
    __shared__ float TH[105][3];

    const int tid = threadIdx.x;
    const int s   = blockIdx.x >> 6;   // 0..7 column slice
    const int b   = blockIdx.x & 63;   // batch
    const int c0  = s * 2;             // output columns c0, c0+1

    const float* vfb = vf + (size_t)b * NVAR * 128;

    // ---- phase 1: P-slice = vf @ W[:, c0:c0+2] (row r, half g per thread) --
    if (tid < 240) {
        const int r = tid >> 1;
        const int g = tid & 1;                 // 0 = S half, 1 = T half
        const float4* va = (const float4*)(vfb + (size_t)r * 128);
        const float*  wb = W + g * 2048 + c0;  // 128 rows x 16 cols per half
        float a0 = 0.f, a1 = 0.f;
        #pragma unroll
        for (int k4 = 0; k4 < 32; k4++) {
            float4 a = va[k4];
            float2 w0 = *(const float2*)(wb + (4 * k4 + 0) * 16);
            float2 w1 = *(const float2*)(wb + (4 * k4 + 1) * 16);
            float2 w2 = *(const float2*)(wb + (4 * k4 + 2) * 16);
            float2 w3 = *(const float2*)(wb + (4 * k4 + 3) * 16);
            a0 = fmaf(a.x, w0.x, a0); a1 = fmaf(a.x, w0.y, a1);
            a0 = fmaf(a.y, w1.x, a0); a1 = fmaf(a.y, w1.y, a1);
            a0 = fmaf(a.z, w2.x, a0); a1 = fmaf(a.z, w2.y, a1);
            a0 = fmaf(a.w, w3.x, a0); a1 = fmaf(a.w, w3.y, a1);
        }
        if (g == 0) {
            Ps[r][0] = a0 + bias[c0];
            Ps[r][1] = a1 + bias[c0 + 1];
        } else {
            Pt[r][0] = a0;
            Pt[r][1] = a1;
        }
    }
    __syncthreads();

    // ---- phase 1.5: h-factor T-means (3x reuse) ---------------------------
    if (tid < 210) {
        int f = tid >> 1, c = tid & 1;
        int u = PAIRS.u[f], v = PAIRS.v[f];
        TH[f][c] = (Pt[u][c] + Pt[v][c] + Pt[15 + f][c]) * (1.0f / 3.0f);
    }
    __syncthreads();

    // ---- phase 2: 680 rows x 2 cols ---------------------------------------
    const float inv3  = 1.0f / 3.0f;
    const float inv14 = 1.0f / 14.0f;
    float* outb = out + (size_t)b * NGRAPH * 16 + c0;

    for (int i = tid; i < NGRAPH; i += 256) {
        float r0, r1;
        if (i < 15) {
            // person u: 14 h-factor neighbors
            float s0 = Ps[i][0], s1 = Ps[i][1];
            float acc0 = 0.f, acc1 = 0.f;
            #pragma unroll
            for (int v2 = 0; v2 < 15; v2++) {
                if (v2 == i) continue;
                int f = pair_index(min(i, v2), max(i, v2));
                acc0 += fmaxf(s0 + TH[f][0], 0.f);
                acc1 += fmaxf(s1 + TH[f][1], 0.f);
            }
            r0 = acc0 * inv14; r1 = acc1 * inv14;
        } else if (i < 120) {
            // pair z-node: 1 h-factor + 13 g-factors
            int f = i - 15;
            int u = PAIRS.u[f], v = PAIRS.v[f];
            float s0 = Ps[i][0], s1 = Ps[i][1];
            float t0 = Pt[i][0], t1 = Pt[i][1];
            float acc0 = fmaxf(s0 + TH[f][0], 0.f);
            float acc1 = fmaxf(s1 + TH[f][1], 0.f);
            #pragma unroll
            for (int w = 0; w < 15; w++) {
                if (w == u || w == v) continue;
                int zuw = 15 + pair_index(min(u, w), max(u, w));
                int zvw = 15 + pair_index(min(v, w), max(v, w));
                float g0 = (t0 + Pt[zuw][0] + Pt[zvw][0]) * inv3;
                float g1 = (t1 + Pt[zuw][1] + Pt[zvw][1]) * inv3;
                acc0 += fmaxf(s0 + g0, 0.f);
                acc1 += fmaxf(s1 + g1, 0.f);
            }
            r0 = acc0 * inv14; r1 = acc1 * inv14;
        } else if (i < 225) {
            // h-factor row: neighbors [u, v, z x12]
            int f = i - 120;
            int u = PAIRS.u[f], v = PAIRS.v[f], z = 15 + f;
            float S0 = (Ps[u][0] + Ps[v][0] + Ps[z][0]) * inv3;
            float S1 = (Ps[u][1] + Ps[v][1] + Ps[z][1]) * inv3;
            r0 = (fmaxf(S0 + Pt[u][0], 0.f) + fmaxf(S0 + Pt[v][0], 0.f)
                + 12.f * fmaxf(S0 + Pt[z][0], 0.f)) * inv14;
            r1 = (fmaxf(S1 + Pt[u][1], 0.f) + fmaxf(S1 + Pt[v][1], 0.f)
                + 12.f * fmaxf(S1 + Pt[z][1], 0.f)) * inv14;
        } else {
            // g-factor row: neighbors [z1, z2, z3 x12]
            int t3 = i - 225;
            int z1 = TRI.z1[t3], z2 = TRI.z2[t3], z3 = TRI.z3[t3];
            float S0 = (Ps[z1][0] + Ps[z2][0] + Ps[z3][0]) * inv3;
            float S1 = (Ps[z1][1] + Ps[z2][1] + Ps[z3][1]) * inv3;
            r0 = (fmaxf(S0 + Pt[z1][0], 0.f) + fmaxf(S0 + Pt[z2][0], 0.f)
                + 12.f * fmaxf(S0 + Pt[z3][0], 0.f)) * inv14;
            r1 = (fmaxf(S1 + Pt[z1][1], 0.f) + fmaxf(S1 + Pt[z2][1], 0.f)
                + 12.f * fmaxf(S1 + Pt[z3][1], 0.f)) * inv14;
        }
        *(float2*)(outb + (size_t)i * 16) = make_float2(r0, r1);
    }
}

extern "C" void kernel_launch(void* const* d_in, const int* in_sizes, int n_in,
                              void* d_out, int out_size, void* d_ws, size_t ws_size,
                              hipStream_t stream) {
    const float* vf   = (const float*)d_in[0];  // [64,120,128]
    const float* W    = (const float*)d_in[1];  // [256,16]
    const float* bias = (const float*)d_in[2];  // [16]
    float* o = (float*)d_out;                   // [64,680,16]

    fgnn_fused<<<512, 256, 0, stream>>>(vf, W, bias, o);
}

// Round 4
// 25.185 us; speedup vs baseline: 1.3451x; 1.0983x over previous
//
#include <hip/hip_runtime.h>

#define NGRAPH 680    // 120 vars + 105 h-factors + 455 g-factors

// pair index for a<b among N=15
__device__ __forceinline__ int pair_index(int a, int b) {
    return a * (29 - a) / 2 + (b - a - 1);
}

// ---- compile-time structure tables (graph is fixed) -----------------------
struct PairTab { unsigned char u[105]; unsigned char v[105]; };
__device__ constexpr PairTab make_pair_tab() {
    PairTab t{};
    int f = 0;
    for (int a = 0; a < 15; a++)
        for (int b = a + 1; b < 15; b++) { t.u[f] = (unsigned char)a; t.v[f] = (unsigned char)b; f++; }
    return t;
}
__device__ constexpr PairTab PAIRS = make_pair_tab();

struct TriTab { unsigned char z1[455]; unsigned char z2[455]; unsigned char z3[455]; };
__device__ constexpr TriTab make_tri_tab() {
    TriTab t{};
    int n = 0;
    for (int i = 0; i < 15; i++)
        for (int j = i + 1; j < 15; j++)
            for (int k = j + 1; k < 15; k++) {
                t.z1[n] = (unsigned char)(15 + i * (29 - i) / 2 + (j - i - 1));
                t.z2[n] = (unsigned char)(15 + i * (29 - i) / 2 + (k - i - 1));
                t.z3[n] = (unsigned char)(15 + j * (29 - j) / 2 + (k - j - 1));
                n++;
            }
    return t;
}
__device__ constexpr TriTab TRI = make_tri_tab();

// Grid: 2048 = (col-slice s 0..7, row-chunk 0..3, batch 0..63), batch minor
// so all 32 blocks of a batch land on XCD b%8 (vf L2-local, out-line merge).
// Phase 1: thread r<120 computes P-row r, 4 cols (S0,S1,T0,T1); W loads are
// lane-invariant -> scalar pipe. Phase 2: 170 output rows, 1 thread each.
__global__ __launch_bounds__(256) void fgnn_fused(
    const float* __restrict__ vf,    // [64][120][128]
    const float* __restrict__ W,     // [256][16]
    const float* __restrict__ bias,  // [16]
    float* __restrict__ out)         // [64][680][16]
{
    __shared__ float Ps[120][2];
    __shared__ float Pt[120][2];
    __shared__ float TH[105][2];

    const int tid   = threadIdx.x;
    const int b     = blockIdx.x & 63;
    const int rem   = blockIdx.x >> 6;
    const int s     = rem >> 2;
    const int chunk = rem & 3;
    const int c0    = s * 2;           // output columns c0, c0+1

    // ---- phase 1: P[r, c0:c0+2] (S and T halves), one row per thread ------
    if (tid < 120) {
        const float4* va = (const float4*)(vf + ((size_t)b * 120 + tid) * 128);
        const float*  Wc = W + c0;     // block-uniform -> scalar loads
        float s0 = 0.f, s1 = 0.f, t0 = 0.f, t1 = 0.f;
        #pragma unroll
        for (int j = 0; j < 32; j++) {
            float4 a = va[j];
            #pragma unroll
            for (int q = 0; q < 4; q++) {
                float av = (q == 0) ? a.x : (q == 1) ? a.y : (q == 2) ? a.z : a.w;
                float2 ws = *(const float2*)(Wc + (4 * j + q) * 16);
                float2 wt = *(const float2*)(Wc + 2048 + (4 * j + q) * 16);
                s0 = fmaf(av, ws.x, s0); s1 = fmaf(av, ws.y, s1);
                t0 = fmaf(av, wt.x, t0); t1 = fmaf(av, wt.y, t1);
            }
        }
        Ps[tid][0] = s0 + bias[c0];
        Ps[tid][1] = s1 + bias[c0 + 1];
        Pt[tid][0] = t0;
        Pt[tid][1] = t1;
    }
    __syncthreads();

    // ---- phase 1.5: h-factor T-means (3x reuse) ---------------------------
    if (tid < 210) {
        int f = tid >> 1, c = tid & 1;
        TH[f][c] = (Pt[PAIRS.u[f]][c] + Pt[PAIRS.v[f]][c] + Pt[15 + f][c]) * (1.0f / 3.0f);
    }
    __syncthreads();

    // ---- phase 2: rows [chunk*170, chunk*170+170), both cols per thread ---
    if (tid < 170) {
        const float inv3  = 1.0f / 3.0f;
        const float inv14 = 1.0f / 14.0f;
        const int i = chunk * 170 + tid;
        float r0, r1;

        if (i < 15) {
            // person u: 14 h-factor neighbors
            float s0 = Ps[i][0], s1 = Ps[i][1];
            float acc0 = 0.f, acc1 = 0.f;
            #pragma unroll
            for (int v2 = 0; v2 < 15; v2++) {
                if (v2 == i) continue;
                int f = pair_index(min(i, v2), max(i, v2));
                acc0 += fmaxf(s0 + TH[f][0], 0.f);
                acc1 += fmaxf(s1 + TH[f][1], 0.f);
            }
            r0 = acc0 * inv14; r1 = acc1 * inv14;
        } else if (i < 120) {
            // pair z-node: 1 h-factor + 13 g-factors
            int f = i - 15;
            int u = PAIRS.u[f], v = PAIRS.v[f];
            float s0 = Ps[i][0], s1 = Ps[i][1];
            float t0 = Pt[i][0], t1 = Pt[i][1];
            float acc0 = fmaxf(s0 + TH[f][0], 0.f);
            float acc1 = fmaxf(s1 + TH[f][1], 0.f);
            #pragma unroll
            for (int w = 0; w < 15; w++) {
                if (w == u || w == v) continue;
                int zuw = 15 + pair_index(min(u, w), max(u, w));
                int zvw = 15 + pair_index(min(v, w), max(v, w));
                acc0 += fmaxf(s0 + (t0 + Pt[zuw][0] + Pt[zvw][0]) * inv3, 0.f);
                acc1 += fmaxf(s1 + (t1 + Pt[zuw][1] + Pt[zvw][1]) * inv3, 0.f);
            }
            r0 = acc0 * inv14; r1 = acc1 * inv14;
        } else if (i < 225) {
            // h-factor row: neighbors [u, v, z x12]
            int f = i - 120;
            int u = PAIRS.u[f], v = PAIRS.v[f], z = 15 + f;
            float S0 = (Ps[u][0] + Ps[v][0] + Ps[z][0]) * inv3;
            float S1 = (Ps[u][1] + Ps[v][1] + Ps[z][1]) * inv3;
            r0 = (fmaxf(S0 + Pt[u][0], 0.f) + fmaxf(S0 + Pt[v][0], 0.f)
                + 12.f * fmaxf(S0 + Pt[z][0], 0.f)) * inv14;
            r1 = (fmaxf(S1 + Pt[u][1], 0.f) + fmaxf(S1 + Pt[v][1], 0.f)
                + 12.f * fmaxf(S1 + Pt[z][1], 0.f)) * inv14;
        } else {
            // g-factor row: neighbors [z1, z2, z3 x12]
            int t3 = i - 225;
            int z1 = TRI.z1[t3], z2 = TRI.z2[t3], z3 = TRI.z3[t3];
            float S0 = (Ps[z1][0] + Ps[z2][0] + Ps[z3][0]) * inv3;
            float S1 = (Ps[z1][1] + Ps[z2][1] + Ps[z3][1]) * inv3;
            r0 = (fmaxf(S0 + Pt[z1][0], 0.f) + fmaxf(S0 + Pt[z2][0], 0.f)
                + 12.f * fmaxf(S0 + Pt[z3][0], 0.f)) * inv14;
            r1 = (fmaxf(S1 + Pt[z1][1], 0.f) + fmaxf(S1 + Pt[z2][1], 0.f)
                + 12.f * fmaxf(S1 + Pt[z3][1], 0.f)) * inv14;
        }
        *(float2*)(out + (size_t)b * NGRAPH * 16 + (size_t)i * 16 + c0) = make_float2(r0, r1);
    }
}

extern "C" void kernel_launch(void* const* d_in, const int* in_sizes, int n_in,
                              void* d_out, int out_size, void* d_ws, size_t ws_size,
                              hipStream_t stream) {
    const float* vf   = (const float*)d_in[0];  // [64,120,128]
    const float* W    = (const float*)d_in[1];  // [256,16]
    const float* bias = (const float*)d_in[2];  // [16]
    float* o = (float*)d_out;                   // [64,680,16]

    fgnn_fused<<<2048, 256, 0, stream>>>(vf, W, bias, o);
}

// Round 5
// 14.533 us; speedup vs baseline: 2.3309x; 1.7329x over previous
//
#include <hip/hip_runtime.h>

#define NGRAPH 680    // 120 vars + 105 h-factors + 455 g-factors

// pair index for a<b among N=15
__device__ __forceinline__ int pair_index(int a, int b) {
    return a * (29 - a) / 2 + (b - a - 1);
}

// ---- compile-time structure tables (graph is fixed) -----------------------
struct PairTab { unsigned char u[105]; unsigned char v[105]; };
__device__ constexpr PairTab make_pair_tab() {
    PairTab t{};
    int f = 0;
    for (int a = 0; a < 15; a++)
        for (int b = a + 1; b < 15; b++) { t.u[f] = (unsigned char)a; t.v[f] = (unsigned char)b; f++; }
    return t;
}
__device__ constexpr PairTab PAIRS = make_pair_tab();

struct TriTab { unsigned char z1[455]; unsigned char z2[455]; unsigned char z3[455]; };
__device__ constexpr TriTab make_tri_tab() {
    TriTab t{};
    int n = 0;
    for (int i = 0; i < 15; i++)
        for (int j = i + 1; j < 15; j++)
            for (int k = j + 1; k < 15; k++) {
                t.z1[n] = (unsigned char)(15 + i * (29 - i) / 2 + (j - i - 1));
                t.z2[n] = (unsigned char)(15 + i * (29 - i) / 2 + (k - i - 1));
                t.z3[n] = (unsigned char)(15 + j * (29 - j) / 2 + (k - j - 1));
                n++;
            }
    return t;
}
__device__ constexpr TriTab TRI = make_tri_tab();

// Grid: 512 = (col-pair s 0..7) x (batch 0..63), batch minor so the 8 blocks
// of one batch land on the same XCD (vf L2-locality + output-line merging).
// 512 threads/block; NO redundant GEMM work (each P-slice computed once).
// Phase 0: stage W[:, c0:c0+2] (both halves) into LDS, layout [128][4].
// Phase 1: thread (row r<120, half g) -> 2 cols, 256 FMA + 128 LDS-broadcast
//          reads + 32 float4 global loads.
// Phase 2: 680 rows x 2 cols over 512 threads.
__global__ __launch_bounds__(512) void fgnn_fused(
    const float* __restrict__ vf,    // [64][120][128]
    const float* __restrict__ W,     // [256][16]
    const float* __restrict__ bias,  // [16]
    float* __restrict__ out)         // [64][680][16]
{
    __shared__ float Wl[128][4];   // [k][S0,S1,T0,T1]
    __shared__ float Ps[120][2];
    __shared__ float Pt[120][2];
    __shared__ float TH[105][2];

    const int tid = threadIdx.x;
    const int s   = blockIdx.x >> 6;   // col-pair
    const int b   = blockIdx.x & 63;   // batch
    const int c0  = s * 2;

    // ---- phase 0: stage W slice ------------------------------------------
    if (tid < 128) {
        float2 ws = *(const float2*)(W + tid * 16 + c0);            // S half
        float2 wt = *(const float2*)(W + (128 + tid) * 16 + c0);    // T half
        Wl[tid][0] = ws.x; Wl[tid][1] = ws.y;
        Wl[tid][2] = wt.x; Wl[tid][3] = wt.y;
    }
    __syncthreads();

    // ---- phase 1: P[r, c0:c0+2] for S and T halves -------------------------
    if (tid < 240) {
        const int r = tid >> 1;
        const int g = tid & 1;          // 0 = S, 1 = T
        const float4* va   = (const float4*)(vf + ((size_t)b * 120 + r) * 128);
        const float2* wcol = (const float2*)&Wl[0][g * 2];  // stride 2 float2/row
        float a0 = 0.f, a1 = 0.f;
        #pragma unroll
        for (int k4 = 0; k4 < 32; k4++) {
            float4 a  = va[k4];
            float2 w0 = wcol[(4 * k4 + 0) * 2];
            float2 w1 = wcol[(4 * k4 + 1) * 2];
            float2 w2 = wcol[(4 * k4 + 2) * 2];
            float2 w3 = wcol[(4 * k4 + 3) * 2];
            a0 = fmaf(a.x, w0.x, a0); a1 = fmaf(a.x, w0.y, a1);
            a0 = fmaf(a.y, w1.x, a0); a1 = fmaf(a.y, w1.y, a1);
            a0 = fmaf(a.z, w2.x, a0); a1 = fmaf(a.z, w2.y, a1);
            a0 = fmaf(a.w, w3.x, a0); a1 = fmaf(a.w, w3.y, a1);
        }
        if (g == 0) {
            Ps[r][0] = a0 + bias[c0];
            Ps[r][1] = a1 + bias[c0 + 1];
        } else {
            Pt[r][0] = a0;
            Pt[r][1] = a1;
        }
    }
    __syncthreads();

    // ---- phase 1.5: h-factor T-means (3x reuse) ----------------------------
    if (tid < 210) {
        int f = tid >> 1, c = tid & 1;
        TH[f][c] = (Pt[PAIRS.u[f]][c] + Pt[PAIRS.v[f]][c] + Pt[15 + f][c]) * (1.0f / 3.0f);
    }
    __syncthreads();

    // ---- phase 2: 680 rows x 2 cols ----------------------------------------
    const float inv3  = 1.0f / 3.0f;
    const float inv14 = 1.0f / 14.0f;
    float* outb = out + (size_t)b * NGRAPH * 16 + c0;

    for (int i = tid; i < NGRAPH; i += 512) {
        float r0, r1;
        if (i < 15) {
            // person u: 14 h-factor neighbors
            float s0 = Ps[i][0], s1 = Ps[i][1];
            float acc0 = 0.f, acc1 = 0.f;
            #pragma unroll
            for (int v2 = 0; v2 < 15; v2++) {
                if (v2 == i) continue;
                int f = pair_index(min(i, v2), max(i, v2));
                acc0 += fmaxf(s0 + TH[f][0], 0.f);
                acc1 += fmaxf(s1 + TH[f][1], 0.f);
            }
            r0 = acc0 * inv14; r1 = acc1 * inv14;
        } else if (i < 120) {
            // pair z-node: 1 h-factor + 13 g-factors
            int f = i - 15;
            int u = PAIRS.u[f], v = PAIRS.v[f];
            float s0 = Ps[i][0], s1 = Ps[i][1];
            float t0 = Pt[i][0], t1 = Pt[i][1];
            float acc0 = fmaxf(s0 + TH[f][0], 0.f);
            float acc1 = fmaxf(s1 + TH[f][1], 0.f);
            #pragma unroll
            for (int w = 0; w < 15; w++) {
                if (w == u || w == v) continue;
                int zuw = 15 + pair_index(min(u, w), max(u, w));
                int zvw = 15 + pair_index(min(v, w), max(v, w));
                acc0 += fmaxf(s0 + (t0 + Pt[zuw][0] + Pt[zvw][0]) * inv3, 0.f);
                acc1 += fmaxf(s1 + (t1 + Pt[zuw][1] + Pt[zvw][1]) * inv3, 0.f);
            }
            r0 = acc0 * inv14; r1 = acc1 * inv14;
        } else if (i < 225) {
            // h-factor row: neighbors [u, v, z x12]
            int f = i - 120;
            int u = PAIRS.u[f], v = PAIRS.v[f], z = 15 + f;
            float S0 = (Ps[u][0] + Ps[v][0] + Ps[z][0]) * inv3;
            float S1 = (Ps[u][1] + Ps[v][1] + Ps[z][1]) * inv3;
            r0 = (fmaxf(S0 + Pt[u][0], 0.f) + fmaxf(S0 + Pt[v][0], 0.f)
                + 12.f * fmaxf(S0 + Pt[z][0], 0.f)) * inv14;
            r1 = (fmaxf(S1 + Pt[u][1], 0.f) + fmaxf(S1 + Pt[v][1], 0.f)
                + 12.f * fmaxf(S1 + Pt[z][1], 0.f)) * inv14;
        } else {
            // g-factor row: neighbors [z1, z2, z3 x12]
            int t3 = i - 225;
            int z1 = TRI.z1[t3], z2 = TRI.z2[t3], z3 = TRI.z3[t3];
            float S0 = (Ps[z1][0] + Ps[z2][0] + Ps[z3][0]) * inv3;
            float S1 = (Ps[z1][1] + Ps[z2][1] + Ps[z3][1]) * inv3;
            r0 = (fmaxf(S0 + Pt[z1][0], 0.f) + fmaxf(S0 + Pt[z2][0], 0.f)
                + 12.f * fmaxf(S0 + Pt[z3][0], 0.f)) * inv14;
            r1 = (fmaxf(S1 + Pt[z1][1], 0.f) + fmaxf(S1 + Pt[z2][1], 0.f)
                + 12.f * fmaxf(S1 + Pt[z3][1], 0.f)) * inv14;
        }
        *(float2*)(outb + (size_t)i * 16) = make_float2(r0, r1);
    }
}

extern "C" void kernel_launch(void* const* d_in, const int* in_sizes, int n_in,
                              void* d_out, int out_size, void* d_ws, size_t ws_size,
                              hipStream_t stream) {
    const float* vf   = (const float*)d_in[0];  // [64,120,128]
    const float* W    = (const float*)d_in[1];  // [256,16]
    const float* bias = (const float*)d_in[2];  // [16]
    float* o = (float*)d_out;                   // [64,680,16]

    fgnn_fused<<<512, 512, 0, stream>>>(vf, W, bias, o);
}